// Round 14
// baseline (619.683 us; speedup 1.0000x reference)
//
#include <hip/hip_runtime.h>

// LSTMAutoRegressive: B=1024, T=1024, H1=64, H2=32, n_in=n_out=1.
// v13 = v12 work-split over 16 waves (1024 thr, 4 waves/SIMD) to fill the
// ~190cyc/step post-barrier latency slack via TLP. Same total issue work:
// A-waves 0-7: 2 L1 tiles each; B-waves 8-15: 1 L2 tile each (+y on w8).
// Weights & h single RTNE bf16; exp2-folded; xd folded as MFMA k-step;
// v_cvt_pk_bf16_f32 h-packing; 1 lgkm-only barrier per step.

using short8 = __attribute__((ext_vector_type(8))) short;
using f32x4  = __attribute__((ext_vector_type(4))) float;
typedef unsigned short us;
typedef unsigned int   uu;

#define MFMA16(A,B,C) __builtin_amdgcn_mfma_f32_16x16x32_bf16((A),(B),(C),0,0,0)
#define BARRIER() asm volatile("s_waitcnt lgkmcnt(0)\n\ts_barrier" ::: "memory")

constexpr int   T     = 1024;
constexpr float LOG2E = 1.44269504088896f;

__device__ __forceinline__ us    bhi(float f){ return (us)(__float_as_uint(f) >> 16); }
__device__ __forceinline__ float hmask(float f){ return __uint_as_float(__float_as_uint(f) & 0xFFFF0000u); }
__device__ __forceinline__ uu rtne(float f){
    uu u = __float_as_uint(f);
    return (u + 0x7FFFu + ((u >> 16) & 1u)) >> 16;
}
__device__ __forceinline__ uu pk_bf16(float lo, float hi){
    uu r;
    asm("v_cvt_pk_bf16_f32 %0, %1, %2" : "=v"(r) : "v"(lo), "v"(hi));
    return r;
}
// h1 pos p -> unit: lane (w,lq) writes units (8w+lq, 8w+4+lq) at pos 8w+2lq(+1)
__device__ __forceinline__ int upos(int p){ return 8*(p>>3) + 4*(p&1) + ((p&7)>>1); }

__device__ __forceinline__ float rcpf(float x){ return __builtin_amdgcn_rcpf(x); }
#if __has_builtin(__builtin_amdgcn_exp2f)
__device__ __forceinline__ float ex2(float x){ return __builtin_amdgcn_exp2f(x); }
#else
__device__ __forceinline__ float ex2(float x){
    float r; asm("v_exp_f32 %0, %1\n\ts_nop 0" : "=v"(r) : "v"(x)); return r;
}
#endif

// gates pre-scaled: i,f,o by -log2e ; g by +2log2e. cs = 2log2e*c carried.
__device__ __forceinline__ float actf(const f32x4 a, float& cs){
    float Ei = ex2(a[0]), Ef = ex2(a[1]), Eg = ex2(a[2]), Eo = ex2(a[3]);
    float si = rcpf(1.0f + Ei), sf = rcpf(1.0f + Ef);
    float rg = rcpf(1.0f + Eg), so = rcpf(1.0f + Eo);
    float gt2 = __builtin_fmaf(-4.0f * LOG2E, rg, 2.0f * LOG2E);   // 2log2e*tanh(g)
    cs = __builtin_fmaf(sf, cs, si * gt2);
    float Ec = ex2(cs);
    float tc = __builtin_fmaf(-2.0f, rcpf(1.0f + Ec), 1.0f);       // tanh(c)
    return so * tc;
}

__global__ __launch_bounds__(1024)
void lstm_ar_kernel(const float* __restrict__ x_in,
                    const float* __restrict__ dly_in,
                    const float* __restrict__ W_ih1, const float* __restrict__ W_hh1,
                    const float* __restrict__ b_ih1, const float* __restrict__ b_hh1,
                    const float* __restrict__ W_ih2, const float* __restrict__ W_hh2,
                    const float* __restrict__ b_ih2, const float* __restrict__ b_hh2,
                    const float* __restrict__ W_out, const float* __restrict__ b_out,
                    float* __restrict__ out)
{
    // h1 rows: upos order, 64 entries + pad, stride 72 us (144B).
    // h2 rows: PLAIN unit order, 32 entries + pad, stride 40 us (80B).
    __shared__ __align__(16) us H1[2][16][72];
    __shared__ __align__(16) us H2[2][16][40];

    const int tid = threadIdx.x, w = tid >> 6, l = tid & 63;
    const int lb = l & 15, lq = l >> 4;
    const int bglob = blockIdx.x * 16 + lb;

    for (int i = tid; i < 2*16*72; i += 1024) ((us*)H1)[i] = 0;
    for (int i = tid; i < 2*16*40; i += 1024) ((us*)H2)[i] = 0;

    const int ty = lb & 3, du = lb >> 2;
    const float srow = (ty == 2) ? 2.0f * LOG2E : -LOG2E;
    const bool isA = (w < 8);
    const int  w2  = w & 7;

    // A role: 2 L1 tiles. B role: 1 L2 tile (+ y on wave 8).
    short8 w1h[2][2], wxd[2];
    short8 w2h[2], whh, wbb;
    short8 wyh = {}, wyl = {};

    if (isA) {
        #pragma unroll
        for (int m = 0; m < 2; ++m) {
            const int G = ty * 64 + 8 * w + 4 * m + du;
            #pragma unroll
            for (int s = 0; s < 2; ++s)
                #pragma unroll
                for (int i = 0; i < 8; ++i) {
                    int p = 32*s + 8*lq + i;
                    float v = srow * W_hh1[G * 64 + upos(p)];
                    w1h[m][s][i] = (short)rtne(v);          // single RTNE bf16
                }
            float q4 = 0.25f * srow;
            float wx = q4 * W_ih1[G*2+0], wd = q4 * W_ih1[G*2+1];
            float bb = q4 * (b_ih1[G] + b_hh1[G]);
            float wxh = hmask(wx), wdh = hmask(wd), bbh = hmask(bb);
            wxd[m] = (short8){ (short)bhi(wx), (short)bhi(wx), (short)bhi(wd),
                               (short)bhi(wd), (short)bhi(bb), (short)bhi(wx - wxh),
                               (short)bhi(wd - wdh), (short)bhi(bb - bbh) };
        }
    } else {
        const int G2 = ty * 32 + 4 * w2 + du;
        #pragma unroll
        for (int s = 0; s < 2; ++s)
            #pragma unroll
            for (int i = 0; i < 8; ++i) {
                int p = 32*s + 8*lq + i;
                float v = srow * W_ih2[G2 * 64 + upos(p)];   // h1 pos-order
                w2h[s][i] = (short)rtne(v);
            }
        #pragma unroll
        for (int i = 0; i < 8; ++i) {
            float v = srow * W_hh2[G2 * 32 + 8*lq + i];      // h2 plain order
            whh[i] = (short)rtne(v);
        }
        float bb = 0.25f * srow * (b_ih2[G2] + b_hh2[G2]);
        float bbh = hmask(bb);
        wbb = (short8){ (short)bhi(bb), (short)bhi(bb - bbh), 0,0,0,0,0,0 };
        if (w == 8) {
            #pragma unroll
            for (int i = 0; i < 8; ++i) {
                float v = (lb == 0) ? W_out[8*lq + i] : 0.0f; // h2 plain order
                float vh = hmask(v);
                wyh[i] = (short)bhi(v);
                wyl[i] = (short)bhi(v - vh);     // y kept exact (wave8 only)
            }
        }
    }
    const float bout = b_out[0];
    const short8 bB = (short8){(short)0x3F80,(short)0x3F80,0,0,0,0,0,0};
    const f32x4  Z4 = {0.f,0.f,0.f,0.f};

    const float* xp = x_in   + bglob * T;
    const float* dp = dly_in + bglob * T;
    float*       op = out    + bglob * T;

    float c1[2] = {0.f,0.f};           // A: 2 units; B: [0] = c2
    float2 xc = {0,0}, dc = {0,0};
    if (isA) { xc = *(const float2*)xp; dc = *(const float2*)dp; }

    __syncthreads();

    auto STEP = [&](const int t, const int pw, const int pr,
                    const float xv, const float dv) {
        if (isA) {
            if (t < T) {
                const us* r1 = &H1[pr][lb][0];
                short8 hh0 = *(const short8*)(r1 + 8*lq);
                short8 hh1 = *(const short8*)(r1 + 32 + 8*lq);
                uu xu = __float_as_uint(xv), duu = __float_as_uint(dv);
                float xlo = xv - __uint_as_float(xu & 0xFFFF0000u);
                float dlo = dv - __uint_as_float(duu & 0xFFFF0000u);
                short8 bx;
                ((uu*)&bx)[0] = (xu >> 16)  | (__float_as_uint(xlo) & 0xFFFF0000u);
                ((uu*)&bx)[1] = (duu >> 16) | (__float_as_uint(dlo) & 0xFFFF0000u);
                ((uu*)&bx)[2] = 0x00003F80u | (xu & 0xFFFF0000u);
                ((uu*)&bx)[3] = (duu >> 16) | 0x3F800000u;

                // single 3-deep chain per tile: wk0 -> xd -> wk1 (2 interleaved)
                f32x4 a[2];
                #pragma unroll
                for (int m = 0; m < 2; ++m) a[m] = MFMA16(w1h[m][0], hh0, Z4);
                #pragma unroll
                for (int m = 0; m < 2; ++m) a[m] = MFMA16(wxd[m],    bx,  a[m]);
                #pragma unroll
                for (int m = 0; m < 2; ++m) a[m] = MFMA16(w1h[m][1], hh1, a[m]);

                float hv[2];
                #pragma unroll
                for (int m = 0; m < 2; ++m) hv[m] = actf(a[m], c1[m]);

                *(uu*)&H1[pw][lb][8*w + 2*lq] = pk_bf16(hv[0], hv[1]);
            }
        } else {
            short8 g0 = {};
            if (t >= 1) {
                const us* r2 = &H2[pw][lb][0];       // h2(t-2), plain order
                g0 = *(const short8*)(r2 + 8*lq);
            }
            // y(t-2) on wave 8
            if (w == 8 && t >= 2) {
                f32x4 yA = MFMA16(wyh, g0, Z4);
                f32x4 yB = MFMA16(wyl, g0, Z4);
                if (lq == 0) op[t-2] = yA[0] + yB[0] + bout;
            }
            // L2: h2(t-1) from h1(t-1) [slot pr] and h2(t-2) [slot pw]
            if (t >= 1 && t <= T) {
                const us* r1 = &H1[pr][lb][0];
                short8 hh0 = *(const short8*)(r1 + 8*lq);
                short8 hh1 = *(const short8*)(r1 + 32 + 8*lq);

                // qA 3-chain (ihk0 -> bias -> ihk1) + qC (hh); 1 merge
                f32x4 qA = MFMA16(w2h[0], hh0, Z4);
                f32x4 qC = MFMA16(whh,    g0,  Z4);
                qA = MFMA16(wbb,    bB,  qA);
                qA = MFMA16(w2h[1], hh1, qA);

                f32x4 g = qA + qC;
                float h2v = actf(g, c1[0]);
                H2[pr][lb][4*w2 + lq] = (us)rtne(h2v);
            }
        }
        BARRIER();
    };

    #pragma unroll 1
    for (int tt = 0; tt <= 512; ++tt) {
        float2 xn = xc, dn = dc;
        if (isA) {
            const int wn = (tt < 511) ? tt + 1 : 511;
            xn = *(const float2*)(xp + 2*wn);
            dn = *(const float2*)(dp + 2*wn);
        }
        STEP(2*tt,     0, 1, xc.x, dc.x);
        STEP(2*tt + 1, 1, 0, xc.y, dc.y);
        xc = xn; dc = dn;
    }
}

extern "C" void kernel_launch(void* const* d_in, const int* in_sizes, int n_in,
                              void* d_out, int out_size, void* d_ws, size_t ws_size,
                              hipStream_t stream) {
    lstm_ar_kernel<<<dim3(64), dim3(1024), 0, stream>>>(
        (const float*)d_in[0],  (const float*)d_in[1],
        (const float*)d_in[2],  (const float*)d_in[3],
        (const float*)d_in[4],  (const float*)d_in[5],
        (const float*)d_in[6],  (const float*)d_in[7],
        (const float*)d_in[8],  (const float*)d_in[9],
        (const float*)d_in[10], (const float*)d_in[11],
        (float*)d_out);
}

// Round 15
// 595.012 us; speedup vs baseline: 1.0415x; 1.0415x over previous
//
#include <hip/hip_runtime.h>

// LSTMAutoRegressive: B=1024, T=1024, H1=64, H2=32, n_in=n_out=1.
// v14 = v12 verbatim (best measured: 597us). v13's TLP split regressed
// (620us) -> additive per-SIMD issue law floor confirmed for this
// decomposition: step = MFMA-issue(326cy) + VALU-issue(884cy) + ~190cy
// residual latency. Structural constraints: 64 CUs (batch-group=MFMA-N=16,
// per-step cross-CU sync impossible at T=1024); precision budget spent
// (absmax 4.88e-4 of 1.07e-3 threshold with h & W single RTNE bf16).
//  - 64 wgs x 512 threads; w0-3: 4 L1 tiles, w4-7: 2 L2 tiles (+y on w4)
//  - MFMA 16x16x32 bf16, swapped operands, gate-permuted A-rows
//  - exp2-folded weights, xd/bias folded as MFMA k-steps
//  - A: 3-deep chain per tile; B: qA 3-chain + qC, single merge
//  - v_cvt_pk_bf16_f32 h-packing; 1 lgkm-only barrier per step

using short8 = __attribute__((ext_vector_type(8))) short;
using f32x4  = __attribute__((ext_vector_type(4))) float;
typedef unsigned short us;
typedef unsigned int   uu;

#define MFMA16(A,B,C) __builtin_amdgcn_mfma_f32_16x16x32_bf16((A),(B),(C),0,0,0)
#define BARRIER() asm volatile("s_waitcnt lgkmcnt(0)\n\ts_barrier" ::: "memory")

constexpr int   T     = 1024;
constexpr float LOG2E = 1.44269504088896f;

__device__ __forceinline__ us    bhi(float f){ return (us)(__float_as_uint(f) >> 16); }
__device__ __forceinline__ float hmask(float f){ return __uint_as_float(__float_as_uint(f) & 0xFFFF0000u); }
__device__ __forceinline__ uu rtne(float f){
    uu u = __float_as_uint(f);
    return (u + 0x7FFFu + ((u >> 16) & 1u)) >> 16;
}
// packed RNE bf16 pair: [15:0]=cvt(lo), [31:16]=cvt(hi)
__device__ __forceinline__ uu pk_bf16(float lo, float hi){
    uu r;
    asm("v_cvt_pk_bf16_f32 %0, %1, %2" : "=v"(r) : "v"(lo), "v"(hi));
    return r;
}
// k-pos -> unit permutations (match packed h write layouts)
__device__ __forceinline__ int upos1(int p){ return 16*(p>>4) + 4*(p&3) + ((p>>2)&3); }
__device__ __forceinline__ int upos2(int p){ return 8*(p>>3) + 4*(p&1) + ((p&7)>>1); }

__device__ __forceinline__ float rcpf(float x){ return __builtin_amdgcn_rcpf(x); }
#if __has_builtin(__builtin_amdgcn_exp2f)
__device__ __forceinline__ float ex2(float x){ return __builtin_amdgcn_exp2f(x); }
#else
__device__ __forceinline__ float ex2(float x){
    float r; asm("v_exp_f32 %0, %1\n\ts_nop 0" : "=v"(r) : "v"(x)); return r;
}
#endif

// gates pre-scaled: i,f,o by -log2e ; g by +2log2e. cs = 2log2e*c carried.
__device__ __forceinline__ float actf(const f32x4 a, float& cs){
    float Ei = ex2(a[0]), Ef = ex2(a[1]), Eg = ex2(a[2]), Eo = ex2(a[3]);
    float si = rcpf(1.0f + Ei), sf = rcpf(1.0f + Ef);
    float rg = rcpf(1.0f + Eg), so = rcpf(1.0f + Eo);
    float gt2 = __builtin_fmaf(-4.0f * LOG2E, rg, 2.0f * LOG2E);   // 2log2e*tanh(g)
    cs = __builtin_fmaf(sf, cs, si * gt2);
    float Ec = ex2(cs);
    float tc = __builtin_fmaf(-2.0f, rcpf(1.0f + Ec), 1.0f);       // tanh(c)
    return so * tc;
}

__global__ __launch_bounds__(512, 2)
void lstm_ar_kernel(const float* __restrict__ x_in,
                    const float* __restrict__ dly_in,
                    const float* __restrict__ W_ih1, const float* __restrict__ W_hh1,
                    const float* __restrict__ b_ih1, const float* __restrict__ b_hh1,
                    const float* __restrict__ W_ih2, const float* __restrict__ W_hh2,
                    const float* __restrict__ b_ih2, const float* __restrict__ b_hh2,
                    const float* __restrict__ W_out, const float* __restrict__ b_out,
                    float* __restrict__ out)
{
    // h1 rows: upos1 order, 64 entries + pad, stride 72 us (144B).
    // h2 rows: upos2 order, 32 entries + pad, stride 40 us (80B).
    __shared__ __align__(16) us H1[2][16][72];
    __shared__ __align__(16) us H2[2][16][40];

    const int tid = threadIdx.x, w = tid >> 6, l = tid & 63;
    const int lb = l & 15, lq = l >> 4;
    const int bglob = blockIdx.x * 16 + lb;

    for (int i = tid; i < 2*16*72; i += 512) ((us*)H1)[i] = 0;
    for (int i = tid; i < 2*16*40; i += 512) ((us*)H2)[i] = 0;

    const int ty = lb & 3, du = lb >> 2;
    const float srow = (ty == 2) ? 2.0f * LOG2E : -LOG2E;
    const bool isA = (w < 4);
    const int  w2  = w & 3;

    // A role: 4 L1 tiles. B role: 2 L2 tiles (+ y on w4).
    short8 w1h[4][2], wxd[4];
    short8 w2h[2][2], whh[2], wbb[2];
    short8 wyh = {}, wyl = {};

    if (isA) {
        #pragma unroll
        for (int m = 0; m < 4; ++m) {
            const int G = ty * 64 + 16 * w + 4 * m + du;
            #pragma unroll
            for (int s = 0; s < 2; ++s)
                #pragma unroll
                for (int i = 0; i < 8; ++i) {
                    int p = 32*s + 8*lq + i;
                    float v = srow * W_hh1[G * 64 + upos1(p)];
                    w1h[m][s][i] = (short)rtne(v);          // single RTNE bf16
                }
            float q4 = 0.25f * srow;
            float wx = q4 * W_ih1[G*2+0], wd = q4 * W_ih1[G*2+1];
            float bb = q4 * (b_ih1[G] + b_hh1[G]);
            float wxh = hmask(wx), wdh = hmask(wd), bbh = hmask(bb);
            wxd[m] = (short8){ (short)bhi(wx), (short)bhi(wx), (short)bhi(wd),
                               (short)bhi(wd), (short)bhi(bb), (short)bhi(wx - wxh),
                               (short)bhi(wd - wdh), (short)bhi(bb - bbh) };
        }
    } else {
        #pragma unroll
        for (int j = 0; j < 2; ++j) {
            const int G2 = ty * 32 + 8 * w2 + 4 * j + du;
            #pragma unroll
            for (int s = 0; s < 2; ++s)
                #pragma unroll
                for (int i = 0; i < 8; ++i) {
                    int p = 32*s + 8*lq + i;
                    float v = srow * W_ih2[G2 * 64 + upos1(p)];   // h1 pos-order
                    w2h[j][s][i] = (short)rtne(v);
                }
            #pragma unroll
            for (int i = 0; i < 8; ++i) {
                float v = srow * W_hh2[G2 * 32 + upos2(8*lq + i)]; // h2 pos-order
                whh[j][i] = (short)rtne(v);
            }
            float bb = 0.25f * srow * (b_ih2[G2] + b_hh2[G2]);
            float bbh = hmask(bb);
            wbb[j] = (short8){ (short)bhi(bb), (short)bhi(bb - bbh), 0,0,0,0,0,0 };
        }
        if (w == 4) {
            #pragma unroll
            for (int i = 0; i < 8; ++i) {
                float v = (lb == 0) ? W_out[upos2(8*lq + i)] : 0.0f;
                float vh = hmask(v);
                wyh[i] = (short)bhi(v);
                wyl[i] = (short)bhi(v - vh);     // y kept exact (wave4 only)
            }
        }
    }
    const float bout = b_out[0];
    const short8 bB = (short8){(short)0x3F80,(short)0x3F80,0,0,0,0,0,0};
    const f32x4  Z4 = {0.f,0.f,0.f,0.f};

    const float* xp = x_in   + bglob * T;
    const float* dp = dly_in + bglob * T;
    float*       op = out    + bglob * T;

    float c1[4] = {0.f,0.f,0.f,0.f};   // A: 4 units; B: [0..1] = c2
    float2 xc = {0,0}, dc = {0,0};
    if (isA) { xc = *(const float2*)xp; dc = *(const float2*)dp; }

    __syncthreads();

    auto STEP = [&](const int t, const int pw, const int pr,
                    const float xv, const float dv) {
        if (isA) {
            if (t < T) {
                const us* r1 = &H1[pr][lb][0];
                short8 hh0 = *(const short8*)(r1 + 8*lq);
                short8 hh1 = *(const short8*)(r1 + 32 + 8*lq);
                uu xu = __float_as_uint(xv), duu = __float_as_uint(dv);
                float xlo = xv - __uint_as_float(xu & 0xFFFF0000u);
                float dlo = dv - __uint_as_float(duu & 0xFFFF0000u);
                short8 bx;
                ((uu*)&bx)[0] = (xu >> 16)  | (__float_as_uint(xlo) & 0xFFFF0000u);
                ((uu*)&bx)[1] = (duu >> 16) | (__float_as_uint(dlo) & 0xFFFF0000u);
                ((uu*)&bx)[2] = 0x00003F80u | (xu & 0xFFFF0000u);
                ((uu*)&bx)[3] = (duu >> 16) | 0x3F800000u;

                // single 3-deep chain per tile: wk0 -> xd -> wk1 (4 interleaved)
                f32x4 a[4];
                #pragma unroll
                for (int m = 0; m < 4; ++m) a[m] = MFMA16(w1h[m][0], hh0, Z4);
                #pragma unroll
                for (int m = 0; m < 4; ++m) a[m] = MFMA16(wxd[m],    bx,  a[m]);
                #pragma unroll
                for (int m = 0; m < 4; ++m) a[m] = MFMA16(w1h[m][1], hh1, a[m]);

                float hv[4];
                #pragma unroll
                for (int m = 0; m < 4; ++m) hv[m] = actf(a[m], c1[m]);

                uint2 P = { pk_bf16(hv[0], hv[1]), pk_bf16(hv[2], hv[3]) };
                *(uint2*)&H1[pw][lb][16*w + 4*lq] = P;
            }
        } else {
            short8 g0 = {};
            if (t >= 1) {
                const us* r2 = &H2[pw][lb][0];       // h2(t-2)
                g0 = *(const short8*)(r2 + 8*lq);
            }
            // y(t-2) on wave 4
            if (w == 4 && t >= 2) {
                f32x4 yA = MFMA16(wyh, g0, Z4);
                f32x4 yB = MFMA16(wyl, g0, Z4);
                if (lq == 0) op[t-2] = yA[0] + yB[0] + bout;
            }
            // L2: h2(t-1) from h1(t-1) [slot pr] and h2(t-2) [slot pw]
            if (t >= 1 && t <= T) {
                const us* r1 = &H1[pr][lb][0];
                short8 hh0 = *(const short8*)(r1 + 8*lq);
                short8 hh1 = *(const short8*)(r1 + 32 + 8*lq);

                // per tile: qA 3-chain (ihk0 -> bias -> ihk1) + qC (hh); 1 merge
                f32x4 qA[2], qC[2];
                #pragma unroll
                for (int j = 0; j < 2; ++j) { qA[j] = MFMA16(w2h[j][0], hh0, Z4);
                                              qC[j] = MFMA16(whh[j],    g0,  Z4); }
                #pragma unroll
                for (int j = 0; j < 2; ++j)   qA[j] = MFMA16(wbb[j],    bB,  qA[j]);
                #pragma unroll
                for (int j = 0; j < 2; ++j)   qA[j] = MFMA16(w2h[j][1], hh1, qA[j]);

                float h2v[2];
                #pragma unroll
                for (int j = 0; j < 2; ++j) {
                    f32x4 g = qA[j] + qC[j];
                    h2v[j] = actf(g, c1[j]);
                }
                *(uu*)&H2[pr][lb][8*w2 + 2*lq] = pk_bf16(h2v[0], h2v[1]);
            }
        }
        BARRIER();
    };

    #pragma unroll 1
    for (int tt = 0; tt <= 512; ++tt) {
        float2 xn = xc, dn = dc;
        if (isA) {
            const int wn = (tt < 511) ? tt + 1 : 511;
            xn = *(const float2*)(xp + 2*wn);
            dn = *(const float2*)(dp + 2*wn);
        }
        STEP(2*tt,     0, 1, xc.x, dc.x);
        STEP(2*tt + 1, 1, 0, xc.y, dc.y);
        xc = xn; dc = dn;
    }
}

extern "C" void kernel_launch(void* const* d_in, const int* in_sizes, int n_in,
                              void* d_out, int out_size, void* d_ws, size_t ws_size,
                              hipStream_t stream) {
    lstm_ar_kernel<<<dim3(64), dim3(512), 0, stream>>>(
        (const float*)d_in[0],  (const float*)d_in[1],
        (const float*)d_in[2],  (const float*)d_in[3],
        (const float*)d_in[4],  (const float*)d_in[5],
        (const float*)d_in[6],  (const float*)d_in[7],
        (const float*)d_in[8],  (const float*)d_in[9],
        (const float*)d_in[10], (const float*)d_in[11],
        (float*)d_out);
}